// Round 4
// baseline (5268.906 us; speedup 1.0000x reference)
//
#include <hip/hip_runtime.h>
#include <math.h>

#define B 128
#define PP 196
#define ENC 2048
#define DEC 512
#define ATTD 512
#define EMB 300
#define VV 10000
#define CAPLEN 51
#define TT 50
#define KPAD 2880          // 512(h) + 300(emb) + 2048(gawe) + 20 pad
#define NPPAD 10112        // pred N padded to 158*64

static const long long OFF_PRED = 0LL;
static const long long OFF_CAPS = 64000000LL;
static const long long OFF_DECL = 64006528LL;
static const long long OFF_ALPH = 64006656LL;
static const long long OFF_SORT = 65261056LL;

typedef unsigned short ushort_t;
typedef unsigned int uint_t;
typedef short bf8 __attribute__((ext_vector_type(8)));
typedef float f4 __attribute__((ext_vector_type(4)));

__device__ __forceinline__ float sigf(float x){ return 1.f/(1.f+expf(-x)); }
__device__ __forceinline__ float b2f(ushort_t u){
  union{uint_t i; float f;} v; v.i = ((uint_t)u)<<16; return v.f;
}
__device__ __forceinline__ ushort_t f2b(float f){
  union{float f; uint_t i;} v; v.f = f;
  uint_t r = v.i + 0x7fffu + ((v.i>>16)&1u);
  return (ushort_t)(r>>16);
}
__device__ __forceinline__ uint_t pack2(float lo, float hi){
  return (uint_t)f2b(lo) | ((uint_t)f2b(hi)<<16);
}
__device__ __forceinline__ float2 b2x2(uint_t u){
  union{uint_t i; float f;} a,b; a.i = u<<16; b.i = u & 0xffff0000u;
  return make_float2(a.f, b.f);
}

// ======== shared 128x64 MFMA tile body, K-prefetched ========
// A[M][K] bf16, B(N,K) row-major bf16. waves 2x2; frags 4x2 of 16x16; BK=32.
__device__ __forceinline__ void gemm128x64(
    const ushort_t* __restrict__ Ab, int lda, int m0,
    const ushort_t* __restrict__ Bb, int ldb, int n0,
    int Kbeg, int Kend, int mbound,
    ushort_t* As, ushort_t* Bs, int tid, f4 acc[4][2])
{
  const int r = tid>>2, cby = (tid&3)*8;
  const int w = tid>>6, l = tid&63;
  const int wm = w>>1, wn = w&1, lr = l&15, lk = (l>>4)*8;
  uint4 qa0 = *(const uint4*)(Ab + (size_t)(m0+r)*lda    + Kbeg + cby);
  uint4 qa1 = *(const uint4*)(Ab + (size_t)(m0+64+r)*lda + Kbeg + cby);
  uint4 qb  = *(const uint4*)(Bb + (size_t)(n0+r)*ldb    + Kbeg + cby);
  for (int k0=Kbeg; k0<Kend; k0+=32){
    __syncthreads();
    *(uint4*)(As + r*40      + cby) = qa0;
    *(uint4*)(As + (64+r)*40 + cby) = qa1;
    *(uint4*)(Bs + r*40      + cby) = qb;
    __syncthreads();
    if (k0+32 < Kend){
      qa0 = *(const uint4*)(Ab + (size_t)(m0+r)*lda    + k0+32 + cby);
      qa1 = *(const uint4*)(Ab + (size_t)(m0+64+r)*lda + k0+32 + cby);
      qb  = *(const uint4*)(Bb + (size_t)(n0+r)*ldb    + k0+32 + cby);
    }
    bf8 b0 = *(const bf8*)(Bs + (wn*32+lr)*40    + lk);
    bf8 b1 = *(const bf8*)(Bs + (wn*32+16+lr)*40 + lk);
    #pragma unroll
    for (int fm=0; fm<4; fm++){
      if (wm*64 + fm*16 < mbound){
        bf8 a = *(const bf8*)(As + (wm*64+fm*16+lr)*40 + lk);
        acc[fm][0] = __builtin_amdgcn_mfma_f32_16x16x32_bf16(a, b0, acc[fm][0], 0, 0, 0);
        acc[fm][1] = __builtin_amdgcn_mfma_f32_16x16x32_bf16(a, b1, acc[fm][1], 0, 0, 0);
      }
    }
  }
}

// ---------------- sort + caps + decode_lengths + sort_ind + nact ----------------
__global__ __launch_bounds__(128) void k_prep(const int* __restrict__ cap_len,
    const int* __restrict__ enc_caps, float* __restrict__ out,
    int* __restrict__ sort_i, int* __restrict__ decl_i, int* __restrict__ caps_i,
    int* __restrict__ nact_d){
  __shared__ int lens[B];
  __shared__ int sind[B];
  __shared__ int s_dl[B];
  int t = threadIdx.x;
  lens[t] = cap_len[t];
  __syncthreads();
  int my = lens[t];
  int rank = 0;
  for (int j=0;j<B;j++){
    int lj = lens[j];
    if (lj > my || (lj == my && j < t)) rank++;
  }
  sind[rank] = t;
  __syncthreads();
  int src = sind[t];
  sort_i[t] = src;
  int dl = lens[src]-1;
  decl_i[t] = dl;
  s_dl[t] = dl;
  out[OFF_DECL+t] = (float)dl;
  out[OFF_SORT+t] = (float)src;
  for (int j=0;j<CAPLEN;j++){
    int v = enc_caps[src*CAPLEN+j];
    caps_i[t*CAPLEN+j] = v;
    out[OFF_CAPS + t*CAPLEN + j] = (float)v;
  }
  __syncthreads();
  if (t < TT){
    int cnt = 0;
    for (int b2=0;b2<B;b2++) cnt += (s_dl[b2] > t) ? 1 : 0;
    nact_d[t] = cnt;
  }
}

// ---------------- mean over P of sorted encoder_out (f32) ----------------
__global__ __launch_bounds__(256) void k_mean(const float* __restrict__ enc,
    const int* __restrict__ sort_i, float* __restrict__ meanb){
  int b = blockIdx.x;
  int e = blockIdx.y*256 + threadIdx.x;
  int sb = sort_i[b];
  const float* p0 = enc + (size_t)sb*PP*ENC + e;
  float s = 0.f;
  for (int p=0;p<PP;p++) s += p0[(size_t)p*ENC];
  meanb[b*ENC+e] = s * (1.0f/PP);
}

// ---------------- h0/c0 f32 (one-time); h0 also -> xb bf16 ----------------
__global__ __launch_bounds__(256) void k_init(const float* __restrict__ meanb,
    const float* __restrict__ Wh, const float* __restrict__ bh,
    const float* __restrict__ Wc, const float* __restrict__ bc,
    float* __restrict__ h, float* __restrict__ c, ushort_t* __restrict__ xb_s){
  __shared__ float aT[64*132];
  __shared__ float wT[64*36];
  int tid = threadIdx.x;
  int n0 = blockIdx.x*32;
  const float* Wm  = blockIdx.y ? Wc : Wh;
  const float* bia = blockIdx.y ? bc : bh;
  float* dst = blockIdx.y ? c : h;
  int bt = tid&15, nt = tid>>4;
  float acc[8][2] = {};
  for (int k0=0;k0<ENC;k0+=64){
    for (int idx=tid; idx<64*128; idx+=256){
      int k=idx&63, m=idx>>6;
      aT[k*132+m] = meanb[m*ENC + k0+k];
    }
    for (int idx=tid; idx<64*32; idx+=256){
      int k=idx&63, n=idx>>6;
      wT[k*36+n] = Wm[(size_t)(n0+n)*ENC + k0+k];
    }
    __syncthreads();
    #pragma unroll 4
    for (int k=0;k<64;k++){
      float a[8], wv[2];
      *(float4*)&a[0] = *(const float4*)&aT[k*132+bt*8];
      *(float4*)&a[4] = *(const float4*)&aT[k*132+bt*8+4];
      *(float2*)&wv[0] = *(const float2*)&wT[k*36+nt*2];
      #pragma unroll
      for (int i=0;i<8;i++){ acc[i][0]+=a[i]*wv[0]; acc[i][1]+=a[i]*wv[1]; }
    }
    __syncthreads();
  }
  #pragma unroll
  for (int i=0;i<8;i++){
    int m = bt*8+i;
    #pragma unroll
    for (int j=0;j<2;j++){
      int n = n0+nt*2+j;
      float v = acc[i][j] + bia[n];
      dst[m*DEC+n] = v;
      if (blockIdx.y == 0) xb_s[(size_t)m*KPAD + n] = f2b(v);
    }
  }
}

// ---------------- weight converters (one-time) ----------------
// interleaved gates layout: dst row n = unit j*4+g  <-  src row g*512+j
__global__ __launch_bounds__(256) void k_wkb(const float* __restrict__ Whh,
    const float* __restrict__ Wih, uint_t* __restrict__ wkb_u){
  int n = blockIdx.x;
  int j = n>>2, g = n&3;
  int rrow = g*512 + j;
  uint_t* dst = wkb_u + (size_t)n*(KPAD/2);
  for (int u=threadIdx.x; u<KPAD/2; u+=256){
    int k = 2*u; float a, bvl;
    if (k < 512){ float2 v = *(const float2*)(Whh + (size_t)rrow*512 + k); a=v.x; bvl=v.y; }
    else if (k < 2860){ float2 v = *(const float2*)(Wih + (size_t)rrow*2348 + (k-512)); a=v.x; bvl=v.y; }
    else { a=0.f; bvl=0.f; }
    dst[u] = pack2(a, bvl);
  }
}
__global__ __launch_bounds__(256) void k_wcatb(const float* __restrict__ Wda,
    const float* __restrict__ Wfb, uint_t* __restrict__ wcat_u){
  int n = blockIdx.x;
  const float* src = (n < 512) ? (Wda + (size_t)n*512) : (Wfb + (size_t)(n-512)*512);
  uint_t* dst = wcat_u + (size_t)n*256;
  int u = threadIdx.x;
  float2 v = *(const float2*)(src + 2*u);
  dst[u] = pack2(v.x, v.y);
}
__global__ __launch_bounds__(256) void k_wfcb(const float* __restrict__ Wfc,
    uint_t* __restrict__ wfc_u){
  int n = blockIdx.x;
  uint_t* dst = wfc_u + (size_t)n*256;
  int u = threadIdx.x;
  if (n < VV){
    float2 v = *(const float2*)(Wfc + (size_t)n*512 + 2*u);
    dst[u] = pack2(v.x, v.y);
  } else dst[u] = 0u;
}
__global__ __launch_bounds__(256) void k_weab(const float* __restrict__ Wea,
    uint_t* __restrict__ wea_u){
  int n = blockIdx.x;
  uint_t* dst = wea_u + (size_t)n*1024;
  for (int u=threadIdx.x; u<1024; u+=256){
    float2 v = *(const float2*)(Wea + (size_t)n*2048 + 2*u);
    dst[u] = pack2(v.x, v.y);
  }
}
__global__ __launch_bounds__(160) void k_embb(const float* __restrict__ embedding,
    const int* __restrict__ caps_i, uint_t* __restrict__ embb_u){
  int b = blockIdx.x, t = blockIdx.y, tid = threadIdx.x;
  if (tid >= 150) return;
  int tok = caps_i[b*CAPLEN+t];
  float2 v = *(const float2*)(embedding + (size_t)tok*EMB + 2*tid);
  embb_u[((size_t)b*TT+t)*150 + tid] = pack2(v.x, v.y);
}
__global__ __launch_bounds__(256) void k_xpad(uint_t* __restrict__ xb_u){
  for (int u=threadIdx.x; u<1280; u+=256){
    int r = u/10, cu = u - r*10;
    xb_u[(size_t)r*(KPAD/2) + 1430 + cu] = 0u;
  }
}
__global__ __launch_bounds__(256) void k_encb(const float* __restrict__ enc,
    const int* __restrict__ sort_i, ushort_t* __restrict__ encb){
  int row = blockIdx.x;
  int b = row/PP, p = row - b*PP;
  int sb = sort_i[b];
  const float4* s4 = (const float4*)(enc + ((size_t)sb*PP+p)*ENC);
  uint4* d4 = (uint4*)(encb + (size_t)row*ENC);
  int tid = threadIdx.x;
  float4 f0 = s4[tid*2], f1 = s4[tid*2+1];
  uint4 q;
  q.x = pack2(f0.x,f0.y); q.y = pack2(f0.z,f0.w);
  q.z = pack2(f1.x,f1.y); q.w = pack2(f1.z,f1.w);
  d4[tid] = q;
}

// ---------------- one-time masked-zero writes for preds + alphas ----------------
__global__ __launch_bounds__(256) void k_zero(const int* __restrict__ decl_i,
    float* __restrict__ out){
  int blk = blockIdx.x;
  int b = blk/TT, t = blk - b*TT;
  if (t < decl_i[b]) return;
  float4 z = {0.f,0.f,0.f,0.f};
  float4* p = (float4*)(out + OFF_PRED + ((size_t)b*TT+t)*VV);
  for (int i=threadIdx.x; i<VV/4; i+=256) p[i] = z;
  size_t ao = (size_t)OFF_ALPH + ((size_t)b*TT+t)*PP;
  if (threadIdx.x < PP) out[ao + threadIdx.x] = 0.f;
}

// ---------------- one-time: att1 = encb @ Wea^T + bea -> attb (MFMA) ----------------
__global__ __launch_bounds__(256) void k_att1g(const ushort_t* __restrict__ encb,
    const ushort_t* __restrict__ weab, const float* __restrict__ bea,
    ushort_t* __restrict__ attb){
  __shared__ ushort_t As[128*40];
  __shared__ ushort_t Bs[64*40];
  int tid = threadIdx.x;
  int m0 = blockIdx.x*128, n0 = blockIdx.y*64;
  f4 acc[4][2] = {};
  gemm128x64(encb, 2048, m0, weab, 2048, n0, 0, 2048, 128, As, Bs, tid, acc);
  int w = tid>>6, l = tid&63, wm = w>>1, wn = w&1;
  #pragma unroll
  for (int fm=0; fm<4; fm++)
    #pragma unroll
    for (int fn=0; fn<2; fn++)
      #pragma unroll
      for (int rr=0; rr<4; rr++){
        int m = m0 + wm*64 + fm*16 + (l>>4)*4 + rr;
        int n = n0 + wn*32 + fn*16 + (l&15);
        attb[(size_t)m*ATTD + n] = f2b(acc[fm][fn][rr] + bea[n]);
      }
}

// ---------------- fallback one-time att1 (f32 VALU, no encb) ----------------
__global__ __launch_bounds__(256) void k_att1_f32(const float* __restrict__ enc,
    const float* __restrict__ Wea, const float* __restrict__ bea,
    const int* __restrict__ sort_i, ushort_t* __restrict__ attb){
  __shared__ float aT[64*132];
  __shared__ float wT[64*68];
  int tid = threadIdx.x;
  int m0 = blockIdx.x*128;
  int n0 = blockIdx.y*64;
  int bt = tid&15, nt = tid>>4;
  float acc[8][4] = {};
  for (int k0=0;k0<ENC;k0+=64){
    for (int idx=tid; idx<64*128; idx+=256){
      int k=idx&63, m=idx>>6;
      int mg = m0+m;
      int b = mg/PP; int p = mg - b*PP;
      int sb = sort_i[b];
      aT[k*132+m] = enc[((size_t)sb*PP + p)*ENC + k0+k];
    }
    for (int idx=tid; idx<64*64; idx+=256){
      int k=idx&63, n=idx>>6;
      wT[k*68+n] = Wea[(size_t)(n0+n)*ENC + k0+k];
    }
    __syncthreads();
    #pragma unroll 4
    for (int k=0;k<64;k++){
      float a[8], wv[4];
      *(float4*)&a[0] = *(const float4*)&aT[k*132+bt*8];
      *(float4*)&a[4] = *(const float4*)&aT[k*132+bt*8+4];
      *(float4*)&wv[0] = *(const float4*)&wT[k*68+nt*4];
      #pragma unroll
      for (int i=0;i<8;i++)
        #pragma unroll
        for (int j=0;j<4;j++) acc[i][j] += a[i]*wv[j];
    }
    __syncthreads();
  }
  #pragma unroll
  for (int i=0;i<8;i++){
    int mg = m0+bt*8+i;
    #pragma unroll
    for (int j=0;j<4;j++){
      int n = n0+nt*4+j;
      attb[(size_t)mg*ATTD + n] = f2b(acc[i][j] + bea[n]);
    }
  }
}

// ---------------- per-step: att2 + gate GEMM (MFMA) ----------------
__global__ __launch_bounds__(256) void k_hmats(const ushort_t* __restrict__ xb,
    const ushort_t* __restrict__ wcatb, const float* __restrict__ bda,
    const float* __restrict__ bfb, const int* __restrict__ nact_d,
    float* __restrict__ att2s, float* __restrict__ gate, int t){
  __shared__ ushort_t As[128*40];
  __shared__ ushort_t Bs[64*40];
  int tid = threadIdx.x;
  int n0 = blockIdx.x*64;
  int mb = nact_d[t];
  f4 acc[4][2] = {};
  gemm128x64(xb, KPAD, 0, wcatb, 512, n0, 0, 512, mb, As, Bs, tid, acc);
  int w = tid>>6, l = tid&63, wm = w>>1, wn = w&1;
  #pragma unroll
  for (int fm=0; fm<4; fm++)
    #pragma unroll
    for (int fn=0; fn<2; fn++)
      #pragma unroll
      for (int rr=0; rr<4; rr++){
        int m = wm*64 + fm*16 + (l>>4)*4 + rr;
        int n = n0 + wn*32 + fn*16 + (l&15);
        float v = acc[fm][fn][rr];
        if (n < 512) att2s[m*512+n] = v + bda[n];
        else         gate[m*2048 + (n-512)] = sigf(v + bfb[n-512]);
      }
}

// ---------------- per-step: score + softmax + alpha-write + awe*gate -> xb ----------------
template<bool FULLT>
__global__ __launch_bounds__(512) void k_score_awe(const ushort_t* __restrict__ attb,
    const float* __restrict__ att2s, const float* __restrict__ wfa,
    const float* __restrict__ bfa, const int* __restrict__ decl_i,
    const float* __restrict__ gate, const ushort_t* __restrict__ encb,
    const float* __restrict__ enc, const int* __restrict__ sort_i,
    float* __restrict__ out, uint_t* __restrict__ xb_u,
    const uint_t* __restrict__ embb_u, const float* __restrict__ embedding,
    const int* __restrict__ caps_i, int t){
  int b = blockIdx.x, tid = threadIdx.x;
  if (t >= decl_i[b]) return;
  __shared__ float s_a2[512], s_w[512], s_sc[200], s_al[200], s_red[8], s_red2[8];
  if (FULLT){
    if (tid < 150) xb_u[b*(KPAD/2) + 256 + tid] = embb_u[((size_t)b*TT+t)*150 + tid];
  } else {
    if (tid < 150){
      int tok = caps_i[b*CAPLEN+t];
      float2 e = *(const float2*)(embedding + (size_t)tok*EMB + 2*tid);
      xb_u[b*(KPAD/2) + 256 + tid] = pack2(e.x, e.y);
    }
  }
  s_a2[tid] = att2s[b*512+tid];
  s_w[tid]  = wfa[tid];
  __syncthreads();
  int wid = tid>>6, lane = tid&63;
  float b0 = bfa[0];
  for (int p=wid; p<PP; p+=8){
    uint4 q = ((const uint4*)(attb + ((size_t)b*PP + p)*ATTD))[lane];
    int j = lane*8;
    float2 x0=b2x2(q.x), x1=b2x2(q.y), x2=b2x2(q.z), x3=b2x2(q.w);
    float s = fmaxf(x0.x+s_a2[j+0],0.f)*s_w[j+0] + fmaxf(x0.y+s_a2[j+1],0.f)*s_w[j+1]
            + fmaxf(x1.x+s_a2[j+2],0.f)*s_w[j+2] + fmaxf(x1.y+s_a2[j+3],0.f)*s_w[j+3]
            + fmaxf(x2.x+s_a2[j+4],0.f)*s_w[j+4] + fmaxf(x2.y+s_a2[j+5],0.f)*s_w[j+5]
            + fmaxf(x3.x+s_a2[j+6],0.f)*s_w[j+6] + fmaxf(x3.y+s_a2[j+7],0.f)*s_w[j+7];
    #pragma unroll
    for (int off=32;off;off>>=1) s += __shfl_down(s,off);
    if (lane==0) s_sc[p] = s + b0;
  }
  __syncthreads();
  float sc = (tid<PP) ? s_sc[tid] : -1e30f;
  float mx = sc;
  #pragma unroll
  for (int off=32;off;off>>=1) mx = fmaxf(mx, __shfl_down(mx,off));
  if (lane==0) s_red[wid] = mx;
  __syncthreads();
  mx = s_red[0];
  #pragma unroll
  for (int i=1;i<8;i++) mx = fmaxf(mx, s_red[i]);
  float e = (tid<PP) ? expf(sc-mx) : 0.f;
  float sm = e;
  #pragma unroll
  for (int off=32;off;off>>=1) sm += __shfl_down(sm,off);
  if (lane==0) s_red2[wid] = sm;
  __syncthreads();
  float tot = 0.f;
  #pragma unroll
  for (int i=0;i<8;i++) tot += s_red2[i];
  float inv = 1.f/tot;
  if (tid<PP){
    float al = e*inv;
    s_al[tid] = al;
    out[(size_t)OFF_ALPH + ((size_t)b*TT+t)*PP + tid] = al;
  }
  __syncthreads();
  // awe: thread owns channels ch=tid*4..+3; then multiply gate, pack to xb
  float a0=0.f,a1=0.f,a2=0.f,a3=0.f;
  if (FULLT){
    const uint2* E = (const uint2*)(encb + (size_t)b*PP*ENC) + tid;
    #pragma unroll 4
    for (int p=0;p<PP;p++){
      float al = s_al[p];
      uint2 q = E[(size_t)p*(ENC/4)];
      float2 u = b2x2(q.x), v = b2x2(q.y);
      a0 += al*u.x; a1 += al*u.y; a2 += al*v.x; a3 += al*v.y;
    }
  } else {
    const float4* E = (const float4*)(enc + (size_t)sort_i[b]*PP*ENC) + tid;
    #pragma unroll 4
    for (int p=0;p<PP;p++){
      float al = s_al[p];
      float4 q = E[(size_t)p*(ENC/4)];
      a0 += al*q.x; a1 += al*q.y; a2 += al*q.z; a3 += al*q.w;
    }
  }
  float4 g = *(const float4*)(gate + b*2048 + tid*4);
  xb_u[b*(KPAD/2) + 406 + tid*2]     = pack2(a0*g.x, a1*g.y);
  xb_u[b*(KPAD/2) + 406 + tid*2 + 1] = pack2(a2*g.z, a3*g.w);
}

// ---------------- per-step: gates GEMM (interleaved) + LSTM cell fused ----------------
__global__ __launch_bounds__(256) void k_b1gf(const ushort_t* __restrict__ xb,
    const ushort_t* __restrict__ wkbi, const float* __restrict__ b_ih,
    const float* __restrict__ b_hh, const int* __restrict__ decl_i,
    const int* __restrict__ nact_d, float* __restrict__ c,
    ushort_t* __restrict__ hnball, ushort_t* __restrict__ xb_s, int t){
  __shared__ ushort_t As[128*40];
  __shared__ ushort_t Bs[64*40];
  __shared__ float sacc[128*68];
  __shared__ float sbias[64];
  __shared__ int s_dl[128];
  int tid = threadIdx.x;
  int n0 = blockIdx.x*64;          // 32 blocks; block owns units j0..j0+15
  int j0 = n0>>2;
  int mb = nact_d[t];
  if (tid < 64){
    int n = n0 + tid;
    int j = n>>2, g = n&3;
    sbias[tid] = b_ih[g*512+j] + b_hh[g*512+j];
  }
  if (tid < 128) s_dl[tid] = decl_i[tid];
  f4 acc[4][2] = {};
  gemm128x64(xb, KPAD, 0, wkbi, KPAD, n0, 0, KPAD, mb, As, Bs, tid, acc);
  int w = tid>>6, l = tid&63, wm = w>>1, wn = w&1;
  __syncthreads();
  #pragma unroll
  for (int fm=0; fm<4; fm++)
    #pragma unroll
    for (int fn=0; fn<2; fn++)
      #pragma unroll
      for (int rr=0; rr<4; rr++){
        int m = wm*64 + fm*16 + (l>>4)*4 + rr;
        int n = wn*32 + fn*16 + (l&15);
        sacc[m*68+n] = acc[fm][fn][rr];
      }
  __syncthreads();
  #pragma unroll
  for (int q=0; q<8; q++){
    int idx = q*256 + tid;
    int m = idx>>4, u = idx&15;
    int j = j0 + u;
    float gi = sacc[m*68 + u*4+0] + sbias[u*4+0];
    float gf = sacc[m*68 + u*4+1] + sbias[u*4+1];
    float gg = sacc[m*68 + u*4+2] + sbias[u*4+2];
    float go = sacc[m*68 + u*4+3] + sbias[u*4+3];
    float cn = sigf(gf)*c[m*512+j] + sigf(gi)*tanhf(gg);
    float hn = sigf(go)*tanhf(cn);
    hnball[((size_t)t*B + m)*512 + j] = f2b(hn);
    if (t < s_dl[m]){
      c[m*512+j] = cn;
      xb_s[(size_t)m*KPAD + j] = f2b(hn);
    }
  }
}

// ---------------- deferred: preds GEMM over all steps ----------------
__global__ __launch_bounds__(256) void k_predall(const ushort_t* __restrict__ hnball,
    const ushort_t* __restrict__ wfcb, const float* __restrict__ b_fc,
    const int* __restrict__ nact_d, float* __restrict__ out){
  __shared__ ushort_t As[128*40];
  __shared__ ushort_t Bs[64*40];
  int tid = threadIdx.x;
  int t = blockIdx.y;
  int n0 = blockIdx.x*64;
  int mb = nact_d[t];
  f4 acc[4][2] = {};
  gemm128x64(hnball + (size_t)t*B*512, 512, 0, wfcb, 512, n0, 0, 512, mb, As, Bs, tid, acc);
  int w = tid>>6, l = tid&63, wm = w>>1, wn = w&1;
  #pragma unroll
  for (int fm=0; fm<4; fm++)
    #pragma unroll
    for (int fn=0; fn<2; fn++)
      #pragma unroll
      for (int rr=0; rr<4; rr++){
        int m = wm*64 + fm*16 + (l>>4)*4 + rr;
        int n = n0 + wn*32 + fn*16 + (l&15);
        if (m < mb && n < VV)
          out[OFF_PRED + ((size_t)m*TT + t)*VV + n] = acc[fm][fn][rr] + b_fc[n];
      }
}

extern "C" void kernel_launch(void* const* d_in, const int* in_sizes, int n_in,
                              void* d_out, int out_size, void* d_ws, size_t ws_size,
                              hipStream_t stream){
  const float* enc       = (const float*)d_in[0];
  const int*   caps_in   = (const int*)d_in[1];
  const int*   caplen    = (const int*)d_in[2];
  const float* W_enc_att = (const float*)d_in[3];
  const float* b_enc_att = (const float*)d_in[4];
  const float* W_dec_att = (const float*)d_in[5];
  const float* b_dec_att = (const float*)d_in[6];
  const float* w_full_att= (const float*)d_in[7];
  const float* b_full_att= (const float*)d_in[8];
  const float* embedding = (const float*)d_in[9];
  const float* W_ih      = (const float*)d_in[10];
  const float* b_ih      = (const float*)d_in[11];
  const float* W_hh      = (const float*)d_in[12];
  const float* b_hh      = (const float*)d_in[13];
  const float* W_init_h  = (const float*)d_in[14];
  const float* b_init_h  = (const float*)d_in[15];
  const float* W_init_c  = (const float*)d_in[16];
  const float* b_init_c  = (const float*)d_in[17];
  const float* W_fbeta   = (const float*)d_in[18];
  const float* b_fbeta   = (const float*)d_in[19];
  const float* W_fc      = (const float*)d_in[20];
  const float* b_fc      = (const float*)d_in[21];
  float* out = (float*)d_out;

  float* W = (float*)d_ws;
  size_t o = 0;
  auto A = [&](size_t n){ float* p = W + o; o += n; return p; };

  bool FULL = ws_size >= 172000000ull;

  float* h      = A(65536);
  float* c      = A(65536);
  float* att2s  = A(65536);
  float* gate   = A(262144);
  float* meanb  = A(262144);
  ushort_t* xb    = (ushort_t*)A(184320);          // 128 x 2880 bf16
  ushort_t* wkb   = (ushort_t*)A(2949120);         // 2048 x 2880 bf16 (interleaved)
  ushort_t* wcatb = (ushort_t*)A(655360);          // 2560 x 512 bf16
  ushort_t* wfcb  = (ushort_t*)A(2588672);         // 10112 x 512 bf16
  ushort_t* hnball= (ushort_t*)A(1638400);         // 50 x 128 x 512 bf16
  ushort_t* attb  = (ushort_t*)A(6422528);         // 25088 x 512 bf16
  int* ip = (int*)A(6848);
  int* sort_i = ip;
  int* decl_i = ip + 128;
  int* nact_d = ip + 256;
  int* caps_i = ip + 320;
  ushort_t* weab = nullptr;
  uint_t*   embb_u = nullptr;
  ushort_t* encb = nullptr;
  if (FULL){
    weab   = (ushort_t*)A(524288);                 // 512 x 2048 bf16
    embb_u = (uint_t*)A(960000);                   // 128 x 50 x 300 bf16
    encb   = (ushort_t*)A(25690112);               // 25088 x 2048 bf16
  }
  uint_t* xb_u = (uint_t*)xb;

  k_prep<<<1,128,0,stream>>>(caplen, caps_in, out, sort_i, decl_i, caps_i, nact_d);
  k_mean<<<dim3(128,8),256,0,stream>>>(enc, sort_i, meanb);
  k_init<<<dim3(16,2),256,0,stream>>>(meanb, W_init_h, b_init_h, W_init_c, b_init_c, h, c, xb);
  k_wkb<<<2048,256,0,stream>>>(W_hh, W_ih, (uint_t*)wkb);
  k_wcatb<<<2560,256,0,stream>>>(W_dec_att, W_fbeta, (uint_t*)wcatb);
  k_wfcb<<<NPPAD,256,0,stream>>>(W_fc, (uint_t*)wfcb);
  k_xpad<<<1,256,0,stream>>>(xb_u);
  k_zero<<<6400,256,0,stream>>>(decl_i, out);
  if (FULL){
    k_weab<<<512,256,0,stream>>>(W_enc_att, (uint_t*)weab);
    k_embb<<<dim3(128,50),160,0,stream>>>(embedding, caps_i, embb_u);
    k_encb<<<25088,256,0,stream>>>(enc, sort_i, encb);
    k_att1g<<<dim3(196,8),256,0,stream>>>(encb, weab, b_enc_att, attb);
  } else {
    k_att1_f32<<<dim3(196,8),256,0,stream>>>(enc, W_enc_att, b_enc_att, sort_i, attb);
  }

  for (int t=0;t<TT;t++){
    k_hmats<<<40,256,0,stream>>>(xb, wcatb, b_dec_att, b_fbeta, nact_d, att2s, gate, t);
    if (FULL)
      k_score_awe<true><<<128,512,0,stream>>>(attb, att2s, w_full_att, b_full_att, decl_i,
          gate, encb, enc, sort_i, out, xb_u, embb_u, embedding, caps_i, t);
    else
      k_score_awe<false><<<128,512,0,stream>>>(attb, att2s, w_full_att, b_full_att, decl_i,
          gate, encb, enc, sort_i, out, xb_u, embb_u, embedding, caps_i, t);
    k_b1gf<<<32,256,0,stream>>>(xb, wkb, b_ih, b_hh, decl_i, nact_d, c, hnball, xb, t);
  }
  k_predall<<<dim3(158,TT),256,0,stream>>>(hnball, wfcb, b_fc, nact_d, out);
}